// Round 9
// baseline (901.611 us; speedup 1.0000x reference)
//
#include <hip/hip_runtime.h>

// Linear(int8-weight, block-sparse) -> quantize -> dequantize, as one fp16 MFMA GEMM.
// out[n,o] = dq(q( (x @ (w_q*mask)^T) * w_scale + bias ))
// N=8192 tokens, O=4096, K=4096.
//
// Numerics: w_q*mask integers in [-127,127] exact in fp16 (validated absmax 0.0625).
//
// GEMM: round-7 base (16x16x32 f16, 256x256, 8-phase, granule-XOR swizzle,
// 0 bank conflicts) + WAVE-GROUP ROLE STAGGER: grp0 (w<4) reads phase c
// while grp1 (w>=4) runs MFMA of phase c-1; roles swap each barrier slot.
// Every slot: 4 waves MFMA (1/SIMD) + 4 waves on LDS -> matrix pipe and
// LDS overlap instead of lockstep-serializing. Equal barrier counts on
// both paths (2/phase); scalar branch via readfirstlane (no exec-masking).
// Per-wave issue/wait ORDER identical to r7 -> same vmcnt ledger:
//   grp0: VMCNT(2|0) after Q_C4/Q_C8 (publish);
//   grp1: VMCNT(2|0) before its C1/C5 reads (same own-issue counts).
// WAR: current-buf stages (c4/c8, A-mh0 panes) are read ONLY by grp0
// (wm0), last read at its c3 slot -> stage issues (both groups) follow.
// 32x32x16 shape REVERTED: its half-wave = 32 rows x 1 k-granule makes
// 4-way quad conflicts unavoidable in 128B row-major panes (round 8:
// 2.5e7 conflicts); 16x16's 16 rows x 2 kq XORs down to free 2-way.

#define M_TOK 8192
#define O_FEAT 4096
#define K_FEAT 4096

#define BM 256
#define BN 256
#define NITER 32            // 64 K-tiles, 2 per iteration

using f16x8 = __attribute__((ext_vector_type(8))) _Float16;
using f32x4 = __attribute__((ext_vector_type(4))) float;

#define BAR()    asm volatile("s_barrier" ::: "memory")
#define LGKM0()  asm volatile("s_waitcnt lgkmcnt(0)" ::: "memory")
#define LGKM8()  asm volatile("s_waitcnt lgkmcnt(8)" ::: "memory")
#define VMCNT(n) asm volatile("s_waitcnt vmcnt(" #n ")" ::: "memory")
#define MFMA16(a, b, c) __builtin_amdgcn_mfma_f32_16x16x32_f16((a), (b), (c), 0, 0, 0)

// ---------------- fp32 -> fp16 conversion of activations ----------------
__global__ __launch_bounds__(256) void cvt_x_kernel(const float* __restrict__ x,
                                                    _Float16* __restrict__ xf) {
    size_t i = ((size_t)blockIdx.x * 256 + threadIdx.x) * 8;
    float4 v0 = *reinterpret_cast<const float4*>(x + i);
    float4 v1 = *reinterpret_cast<const float4*>(x + i + 4);
    f16x8 h;
    h[0] = (_Float16)v0.x; h[1] = (_Float16)v0.y;
    h[2] = (_Float16)v0.z; h[3] = (_Float16)v0.w;
    h[4] = (_Float16)v1.x; h[5] = (_Float16)v1.y;
    h[6] = (_Float16)v1.z; h[7] = (_Float16)v1.w;
    *reinterpret_cast<f16x8*>(xf + i) = h;
}

// ------------- fuse block mask into fp16 weights (exact ints) -----------
__global__ __launch_bounds__(256) void cvt_w_kernel(const float* __restrict__ wq,
                                                    const int* __restrict__ mask,
                                                    _Float16* __restrict__ wf) {
    size_t i = ((size_t)blockIdx.x * 256 + threadIdx.x) * 8;  // 8 weights = 2 mask blocks
    float4 v0 = *reinterpret_cast<const float4*>(wq + i);
    float4 v1 = *reinterpret_cast<const float4*>(wq + i + 4);
    int2 mv = *reinterpret_cast<const int2*>(mask + i / 4);
    float m0 = mv.x ? 1.0f : 0.0f;
    float m1 = mv.y ? 1.0f : 0.0f;
    f16x8 h;
    h[0] = (_Float16)(v0.x * m0); h[1] = (_Float16)(v0.y * m0);
    h[2] = (_Float16)(v0.z * m0); h[3] = (_Float16)(v0.w * m0);
    h[4] = (_Float16)(v1.x * m1); h[5] = (_Float16)(v1.y * m1);
    h[6] = (_Float16)(v1.z * m1); h[7] = (_Float16)(v1.w * m1);
    *reinterpret_cast<f16x8*>(wf + i) = h;
}

// ---------------- 256x256 staggered 8-phase fp16 MFMA GEMM --------------
// A [8192][4096] f16 row-major, B [4096][4096] f16 row-major (B^T GEMM).
// LDS byte layout: mat*65536 + buf*32768 + mhalf*16384 + row*128 + swz(col).
__global__ __launch_bounds__(512, 2) void gemm_kernel(const _Float16* __restrict__ A,
                                                      const _Float16* __restrict__ B,
                                                      const float* __restrict__ bias,
                                                      const float* __restrict__ wsp,
                                                      const float* __restrict__ osp,
                                                      float* __restrict__ C) {
    __shared__ __align__(16) unsigned char smem[131072];
    char* smc = (char*)smem;

    const int tid  = threadIdx.x;
    const int lane = tid & 63;
    const int w    = tid >> 6;      // 0..7
    const int wm   = w >> 2;        // 0..1  (M half) == wave group
    const int wn   = w & 3;         // 0..3  (N quarter)
    const int lr   = lane & 15;     // fragment row/col
    const int kq   = lane >> 4;     // 0..3  k-granule

    const int bm = blockIdx.x >> 4; // 32 M-tiles
    const int bn = blockIdx.x & 15; // 16 N-tiles

    // ---- read bases (swizzled, per-thread; kh flips byte-bit6) ----
    const int laneSwz = lr * 128 + ((kq ^ (lr & 3)) << 4) + (((lr >> 2) & 1) << 6);
    const char* aK0 = smc + wm * 16384 + laneSwz;
    const char* aK1 = smc + wm * 16384 + (laneSwz ^ 64);
    const char* bK0 = smc + 65536 + (wn >> 1) * 16384 + (wn & 1) * 8192 + laneSwz;
    const char* bK1 = smc + 65536 + (wn >> 1) * 16384 + (wn & 1) * 8192 + (laneSwz ^ 64);

    // ---- stage geometry: linear LDS dst, inverse-swizzled global src ----
    const int gs = (tid & 7) ^ ((tid >> 3) & 7);   // source 16B granule
    const _Float16* pAsrc = A + (size_t)(bm * BM + (tid >> 3)) * K_FEAT + gs * 8;
    const _Float16* pBsrc = B + (size_t)(bn * BN + (tid >> 3)) * K_FEAT + gs * 8;
    char* dstT = smc + tid * 16;

    auto gload = [&](const _Float16* src, char* dst) {
        __builtin_amdgcn_global_load_lds(
            (const __attribute__((address_space(1))) void*)(const void*)src,
            (__attribute__((address_space(3))) void*)(void*)dst, 16, 0, 0);
    };
    auto stgA = [&](int buf, int mh, int kElem) {   // one A pane = 2 gloads
#pragma unroll
        for (int j = 0; j < 2; ++j)
            gload(pAsrc + (size_t)(mh * 128 + j * 64) * K_FEAT + kElem,
                  dstT + buf * 32768 + mh * 16384 + j * 8192);
    };
    auto stgB = [&](int buf, int mh, int kElem) {   // one B pane = 2 gloads
#pragma unroll
        for (int j = 0; j < 2; ++j)
            gload(pBsrc + (size_t)(mh * 128 + j * 64) * K_FEAT + kElem,
                  dstT + 65536 + buf * 32768 + mh * 16384 + j * 8192);
    };

    auto rdA = [&](int m, int kh, int buf) -> f16x8 {
        return *reinterpret_cast<const f16x8*>((kh ? aK1 : aK0) + buf * 32768 + m * 2048);
    };
    auto rdB = [&](int n, int kh, int buf) -> f16x8 {
        return *reinterpret_cast<const f16x8*>((kh ? bK1 : bK0) + buf * 32768 + n * 2048);
    };

    f32x4 acc[8][4] = {};
    f16x8 aR[8], bA[4], bB[4];

#define RD_A(MB, BUF) _Pragma("unroll") for (int kh = 0; kh < 2; ++kh) \
    _Pragma("unroll") for (int mi = 0; mi < 4; ++mi) aR[kh * 4 + mi] = rdA((MB) + mi, kh, BUF)
#define RD_BV(DST, NB, BUF) _Pragma("unroll") for (int kh = 0; kh < 2; ++kh) \
    _Pragma("unroll") for (int ni = 0; ni < 2; ++ni) DST[kh * 2 + ni] = rdB((NB) + ni, kh, BUF)
#define QUAD(MS, NS, BV) do { _Pragma("unroll") for (int kh = 0; kh < 2; ++kh) \
    _Pragma("unroll") for (int mi = 0; mi < 4; ++mi) \
    _Pragma("unroll") for (int ni = 0; ni < 2; ++ni) \
        acc[(MS) * 4 + mi][(NS) * 2 + ni] = \
            MFMA16(aR[kh * 4 + mi], BV[kh * 2 + ni], acc[(MS) * 4 + mi][(NS) * 2 + ni]); } while (0)
#define PRIO1() __builtin_amdgcn_s_setprio(1)
#define PRIO0() __builtin_amdgcn_s_setprio(0)
// phase read/stage/mfma bundles (c4/c8 have no reads: bA stays live c1->c4)
#define RD_C1(B)  do { RD_A(0, B); RD_BV(bA, 0, B); } while (0)
#define RD_C2(B)  RD_BV(bB, 2, B)
#define RD_C3(B)  RD_A(4, B)
#define Q_C1 QUAD(0, 0, bA)
#define Q_C2 QUAD(0, 1, bB)
#define Q_C3 QUAD(1, 1, bB)
#define Q_C4 QUAD(1, 0, bA)

    const bool g0 = __builtin_amdgcn_readfirstlane(wm) == 0;

    // ---- prologue (all waves): K-tile0 panes (8 loads) + A(1,mh0) (2) ----
    stgA(0, 0, 0); stgA(0, 1, 0); stgB(0, 0, 0); stgB(0, 1, 0);
    stgA(1, 0, 64);
    VMCNT(2);       // K-tile0 landed; A(1,mh0) in flight
    BAR();

    int kOff = 0;   // elem K-offset of K-tile s0 = 2t
    for (int t = 0; t < NITER; ++t) {
        const bool more = (t + 1 < NITER);

        // ---------------- phase c1 ----------------
        if (g0) { RD_C1(0); stgA(1, 1, kOff + 64); LGKM8(); }
        else if (t) { LGKM0(); PRIO1(); Q_C4 /* c8 of prev, buf1 */; PRIO0(); }
        BAR();
        if (g0) { LGKM0(); PRIO1(); Q_C1; PRIO0(); }
        else    { VMCNT(2); RD_C1(0); stgA(1, 1, kOff + 64); LGKM8(); }
        BAR();

        // ---------------- phase c2 ----------------
        if (g0) { RD_C2(0); stgB(1, 0, kOff + 64); }
        else    { LGKM0(); PRIO1(); Q_C1; PRIO0(); }
        BAR();
        if (g0) { LGKM0(); PRIO1(); Q_C2; PRIO0(); }
        else    { RD_C2(0); stgB(1, 0, kOff + 64); }
        BAR();

        // ---------------- phase c3 ----------------
        if (g0) { RD_C3(0); stgB(1, 1, kOff + 64); }
        else    { LGKM0(); PRIO1(); Q_C2; PRIO0(); }
        BAR();
        if (g0) { LGKM0(); PRIO1(); Q_C3; PRIO0(); }
        else    { RD_C3(0); stgB(1, 1, kOff + 64); }
        BAR();

        // ---------------- phase c4 ----------------
        if (g0) { if (more) stgA(0, 0, kOff + 128); }
        else    { LGKM0(); PRIO1(); Q_C3; PRIO0(); }
        BAR();
        if (g0) { PRIO1(); Q_C4; PRIO0();
                  if (more) { VMCNT(2); } else { VMCNT(0); } }
        else    { if (more) stgA(0, 0, kOff + 128); }
        BAR();

        // ---------------- phase c5 ----------------
        if (g0) { RD_C1(1); if (more) stgA(0, 1, kOff + 128); LGKM8(); }
        else    { LGKM0(); PRIO1(); Q_C4 /* c4, buf0 */; PRIO0(); }
        BAR();
        if (g0) { LGKM0(); PRIO1(); Q_C1; PRIO0(); }
        else    { if (more) { VMCNT(2); } else { VMCNT(0); }
                  RD_C1(1); if (more) stgA(0, 1, kOff + 128); LGKM8(); }
        BAR();

        // ---------------- phase c6 ----------------
        if (g0) { RD_C2(1); if (more) stgB(0, 0, kOff + 128); }
        else    { LGKM0(); PRIO1(); Q_C1; PRIO0(); }
        BAR();
        if (g0) { LGKM0(); PRIO1(); Q_C2; PRIO0(); }
        else    { RD_C2(1); if (more) stgB(0, 0, kOff + 128); }
        BAR();

        // ---------------- phase c7 ----------------
        if (g0) { RD_C3(1); if (more) stgB(0, 1, kOff + 128); }
        else    { LGKM0(); PRIO1(); Q_C2; PRIO0(); }
        BAR();
        if (g0) { LGKM0(); PRIO1(); Q_C3; PRIO0(); }
        else    { RD_C3(1); if (more) stgB(0, 1, kOff + 128); }
        BAR();

        // ---------------- phase c8 ----------------
        if (g0) { if (more) stgA(1, 0, kOff + 192); }
        else    { LGKM0(); PRIO1(); Q_C3; PRIO0(); }
        BAR();
        if (g0) { PRIO1(); Q_C4; PRIO0(); if (more) { VMCNT(2); } }
        else    { if (more) stgA(1, 0, kOff + 192); }
        BAR();

        kOff += 128;
    }
    // grp1 trailing MFMA: c8 quad of the last K-tile (buf1 regs still live)
    if (!g0) { LGKM0(); PRIO1(); Q_C4; PRIO0(); }

    // ---------------- fused epilogue: scale + bias + quant + dequant ----
    const float wscale = wsp[0];
    const float oscale = osp[0];
    const int row0 = bm * BM + wm * 128;
    const int col0 = bn * BN + wn * 64;
#pragma unroll
    for (int n = 0; n < 4; ++n) {
        const int col = col0 + n * 16 + lr;
        const float bc = bias[col];
#pragma unroll
        for (int m = 0; m < 8; ++m) {
#pragma unroll
            for (int j = 0; j < 4; ++j) {
                const int row = row0 + m * 16 + kq * 4 + j;
                float y = acc[m][n][j] * wscale + bc;
                float q = rintf(y / oscale);          // round-half-even, matches jnp.round
                q = fminf(fmaxf(q, -128.0f), 127.0f);
                C[(size_t)row * O_FEAT + col] = q * oscale;
            }
        }
    }
#undef RD_A
#undef RD_BV
#undef QUAD
#undef RD_C1
#undef RD_C2
#undef RD_C3
#undef Q_C1
#undef Q_C2
#undef Q_C3
#undef Q_C4
#undef PRIO1
#undef PRIO0
}

extern "C" void kernel_launch(void* const* d_in, const int* in_sizes, int n_in,
                              void* d_out, int out_size, void* d_ws, size_t ws_size,
                              hipStream_t stream) {
    const float* x        = (const float*)d_in[0];  // [8192,4096] fp32
    const float* wq       = (const float*)d_in[1];  // [4096,4096] fp32 (int8 values)
    const float* bias     = (const float*)d_in[2];  // [4096]
    const float* w_scale  = (const float*)d_in[3];  // scalar
    const float* out_scale= (const float*)d_in[4];  // scalar
    const int*   mask     = (const int*)d_in[5];    // [4096,1024] int32
    float* out = (float*)d_out;

    _Float16* xf = (_Float16*)d_ws;                                        // 64 MiB
    _Float16* wf = (_Float16*)((char*)d_ws + (size_t)M_TOK * K_FEAT * 2);  // +32 MiB

    cvt_x_kernel<<<(M_TOK * (size_t)K_FEAT) / 8 / 256, 256, 0, stream>>>(x, xf);
    cvt_w_kernel<<<(O_FEAT * (size_t)K_FEAT) / 8 / 256, 256, 0, stream>>>(wq, mask, wf);

    // (8192/256) x (4096/256) = 32*16 = 512 blocks, 512 threads
    gemm_kernel<<<dim3((M_TOK / BM) * (O_FEAT / BN)), 512, 0, stream>>>(
        xf, wf, bias, w_scale, out_scale, out);
}

// Round 11
// 295.074 us; speedup vs baseline: 3.0555x; 3.0555x over previous
//
#include <hip/hip_runtime.h>

// Linear(int8-weight, block-sparse) -> quantize -> dequantize, as one fp16 MFMA GEMM.
// out[n,o] = dq(q( (x @ (w_q*mask)^T) * w_scale + bias ))
// N=8192 tokens, O=4096, K=4096.
//
// Numerics: w_q*mask integers in [-127,127] exact in fp16 (validated absmax 0.0625).
//
// GEMM: r5's proven-correct fragment-pipelined structure (16x16x32, 256x256,
// BK=64, 16 fragment regs, granule-XOR swizzle, 0 conflicts) restructured
// for LDS<->MFMA OVERLAP: ONE barrier per phase (4/K-tile), reads for the
// next MFMA cluster issued BEFORE the current cluster, and explicit counted
// lgkmcnt + sched_barrier(0) so each cluster waits only for the previous
// phase's reads (which completed under the previous MFMA). Rationale: all
// four 245us schedules measured MFMA-busy(2483cyc) + LDS-busy(2304cyc) ~=
// K-tile time(4594cyc) -- the units were lockstep-SERIALIZED. Overlap
// ceiling ~= max(2483,2304)+barriers ~= 3000cyc -> ~165us.
// Wait audit (per phase: outstanding DS at LGKM = just-issued only):
//   P1 reads a1=A47k0[4];  LGKM(4) drains P4's a0/b0v -> MFMA m03k0(a0,b0v)
//   P2 reads a0=A03k1+b1v[8]; LGKM(8) drains P1's a1 -> MFMA m47k0(a1,b0v)
//   P3 reads a1=A47k1[4];  LGKM(4) drains P2's      -> MFMA m03k1(a0,b1v)
//   P4 reads a0'/b0v'(s+1)[8]; LGKM(8) drains P3's  -> MFMA m47k1(a1,b1v)
// Stage ledger = r5's exactly (P1:A_k0(s+1), P2:B_k0(s+1), P3:A_k1(s+1),
// P4:B_k1(s+1), all into next buf; publish VMCNT(2) end-P1 [kh1(s)] and
// end-P3 [kh0(s+1)]). Pane WAR margins >=3 phases (audited per-pane).
// r10's stage-into-current-buf bug REVERTED (A panes are read at c1 AND c3).

#define M_TOK 8192
#define O_FEAT 4096
#define K_FEAT 4096

#define BM 256
#define BN 256
#define BK 64
#define NT (K_FEAT / BK)   // 64 K-tiles

// LDS element strides for smem[2][2][2][BM*32]: buf=32768, mat=16384, kh=8192
#define S_BUF 32768
#define S_MAT 16384
#define S_KH  8192

using f16x8 = __attribute__((ext_vector_type(8))) _Float16;
using f32x4 = __attribute__((ext_vector_type(4))) float;

#define BAR()    asm volatile("s_barrier" ::: "memory")
#define LGKM(n)  asm volatile("s_waitcnt lgkmcnt(" #n ")" ::: "memory")
#define VMCNT(n) asm volatile("s_waitcnt vmcnt(" #n ")" ::: "memory")
#define SB0()    __builtin_amdgcn_sched_barrier(0)
#define MFMA16(a, b, c) __builtin_amdgcn_mfma_f32_16x16x32_f16((a), (b), (c), 0, 0, 0)

// ---------------- fp32 -> fp16 conversion of activations ----------------
__global__ __launch_bounds__(256) void cvt_x_kernel(const float* __restrict__ x,
                                                    _Float16* __restrict__ xf) {
    size_t i = ((size_t)blockIdx.x * 256 + threadIdx.x) * 8;
    float4 v0 = *reinterpret_cast<const float4*>(x + i);
    float4 v1 = *reinterpret_cast<const float4*>(x + i + 4);
    f16x8 h;
    h[0] = (_Float16)v0.x; h[1] = (_Float16)v0.y;
    h[2] = (_Float16)v0.z; h[3] = (_Float16)v0.w;
    h[4] = (_Float16)v1.x; h[5] = (_Float16)v1.y;
    h[6] = (_Float16)v1.z; h[7] = (_Float16)v1.w;
    *reinterpret_cast<f16x8*>(xf + i) = h;
}

// ------------- fuse block mask into fp16 weights (exact ints) -----------
__global__ __launch_bounds__(256) void cvt_w_kernel(const float* __restrict__ wq,
                                                    const int* __restrict__ mask,
                                                    _Float16* __restrict__ wf) {
    size_t i = ((size_t)blockIdx.x * 256 + threadIdx.x) * 8;  // 8 weights = 2 mask blocks
    float4 v0 = *reinterpret_cast<const float4*>(wq + i);
    float4 v1 = *reinterpret_cast<const float4*>(wq + i + 4);
    int2 mv = *reinterpret_cast<const int2*>(mask + i / 4);
    float m0 = mv.x ? 1.0f : 0.0f;
    float m1 = mv.y ? 1.0f : 0.0f;
    f16x8 h;
    h[0] = (_Float16)(v0.x * m0); h[1] = (_Float16)(v0.y * m0);
    h[2] = (_Float16)(v0.z * m0); h[3] = (_Float16)(v0.w * m0);
    h[4] = (_Float16)(v1.x * m1); h[5] = (_Float16)(v1.y * m1);
    h[6] = (_Float16)(v1.z * m1); h[7] = (_Float16)(v1.w * m1);
    *reinterpret_cast<f16x8*>(wf + i) = h;
}

// ---------------- 256x256 overlapped 4-phase fp16 MFMA GEMM -------------
// A [8192][4096] f16 row-major, B [4096][4096] f16 row-major (B^T GEMM).
// Swizzle: 16B granule kq -> kq ^ ((row>>1)&3); linear LDS dest +
// inverse-permuted global src (global_load_lds), same XOR on ds_read.
__global__ __launch_bounds__(512, 2) void gemm_kernel(const _Float16* __restrict__ A,
                                                      const _Float16* __restrict__ B,
                                                      const float* __restrict__ bias,
                                                      const float* __restrict__ wsp,
                                                      const float* __restrict__ osp,
                                                      float* __restrict__ C) {
    __shared__ __align__(16) _Float16 smem[2][2][2][BM * 32];
    _Float16* sm = &smem[0][0][0][0];

    const int tid  = threadIdx.x;
    const int lane = tid & 63;
    const int w    = tid >> 6;      // 0..7
    const int wm   = w >> 2;        // 0..1  (M half)
    const int wn   = w & 3;         // 0..3  (N quarter)
    const int lr   = lane & 15;     // fragment row/col
    const int kq   = lane >> 4;     // 0..3  k-granule

    const int bm = blockIdx.x >> 4; // 32 M-tiles
    const int bn = blockIdx.x & 15; // 16 N-tiles

    // ---- staging geometry (hoisted advancing pointers) ----
    const int sr0  = w * 32 + (lane >> 2);
    const int csrc = ((lane & 3) ^ ((lane >> 3) & 3)) * 8;  // inverse-swizzled src granule
    const size_t J1 = (size_t)16 * K_FEAT;                  // j=1 source row offset

    const _Float16* pA0 = A + (size_t)(bm * BM + sr0) * K_FEAT + csrc;  // A kh0
    const _Float16* pA1 = pA0 + 32;                                      // A kh1
    const _Float16* pB0 = B + (size_t)(bn * BN + sr0) * K_FEAT + csrc;  // B kh0
    const _Float16* pB1 = pB0 + 32;                                      // B kh1

    const int dst0 = (w * 128 + lane) * 8;   // j=0 LDS dst elem offset within a pane
    const int dst1 = dst0 + 64 * 8;          // j=1

    auto stg = [&](const _Float16* src, _Float16* dstp) {
        __builtin_amdgcn_global_load_lds(
            (const __attribute__((address_space(1))) void*)(const void*)src,
            (__attribute__((address_space(3))) void*)(void*)dstp, 16, 0, 0);
    };

    // ---- fragment read offsets (hoisted, swizzled) ----
    int offA[4], offB[4];
#pragma unroll
    for (int m = 0; m < 4; ++m) {
        const int r = wm * 128 + m * 16 + lr;
        offA[m] = r * 32 + ((kq ^ ((r >> 1) & 3)) << 3);
    }
#pragma unroll
    for (int n = 0; n < 4; ++n) {
        const int r = wn * 64 + n * 16 + lr;
        offB[n] = r * 32 + ((kq ^ ((r >> 1) & 3)) << 3);
    }
    auto rd = [&](const _Float16* sbuf, int off, int immE) -> f16x8 {
        return *reinterpret_cast<const f16x8*>(sbuf + off + immE);  // immE folds into ds offset
    };

    f32x4 acc[8][4] = {};
    f16x8 a0[4], a1[4], b0v[4], b1v[4];

    // ---- prologue: stage tile0 (kh0 then kh1); publish kh0; prime P1 frags ----
    stg(pA0, sm + dst0);                    stg(pA0 + J1, sm + dst1);
    stg(pB0, sm + S_MAT + dst0);            stg(pB0 + J1, sm + S_MAT + dst1);
    stg(pA1, sm + S_KH + dst0);             stg(pA1 + J1, sm + S_KH + dst1);
    stg(pB1, sm + S_MAT + S_KH + dst0);     stg(pB1 + J1, sm + S_MAT + S_KH + dst1);
    VMCNT(4);   // kh0(0) landed; kh1(0) in flight
    BAR();
#pragma unroll
    for (int m = 0; m < 4; ++m) a0[m] = rd(sm, offA[m], 0);
#pragma unroll
    for (int n = 0; n < 4; ++n) b0v[n] = rd(sm, offB[n], S_MAT);
    pA0 += BK; pA1 += BK; pB0 += BK; pB1 += BK;   // -> t=1

    for (int s = 0; s < NT; ++s) {
        const _Float16* sb = sm + ((s & 1) ? S_BUF : 0);   // current buf
        _Float16*       sn = sm + ((s & 1) ? 0 : S_BUF);   // next buf
        const bool more = (s + 1 < NT);

        // ---- P1: read a47_k0[4]; stage A_k0(s+1); MFMA m0-3 x kh0; publish kh1(s) ----
#pragma unroll
        for (int m = 0; m < 4; ++m) a1[m] = rd(sb, offA[m], 2048);
        if (more) { stg(pA0, sn + dst0); stg(pA0 + J1, sn + dst1); }
        LGKM(4);   // drain P4(s-1)'s a0/b0v (completed under P4's MFMA)
        SB0();
        __builtin_amdgcn_s_setprio(1);
#pragma unroll
        for (int m = 0; m < 4; ++m)
#pragma unroll
            for (int n = 0; n < 4; ++n)
                acc[m][n] = MFMA16(a0[m], b0v[n], acc[m][n]);
        __builtin_amdgcn_s_setprio(0);
        // publish kh1(s): A_k1(s)[P3(s-1)], B_k1(s)[P4(s-1)] landed; only
        // P1's own 2 stage-loads may remain in flight.
        if (more) { VMCNT(2); } else { VMCNT(0); }
        BAR();

        // ---- P2: read a03_k1 + b_k1[8]; stage B_k0(s+1); MFMA m4-7 x kh0 ----
#pragma unroll
        for (int m = 0; m < 4; ++m) a0[m] = rd(sb, offA[m], S_KH);
#pragma unroll
        for (int n = 0; n < 4; ++n) b1v[n] = rd(sb, offB[n], S_MAT + S_KH);
        if (more) { stg(pB0, sn + S_MAT + dst0); stg(pB0 + J1, sn + S_MAT + dst1); }
        LGKM(8);   // drain P1's a1
        SB0();
        __builtin_amdgcn_s_setprio(1);
#pragma unroll
        for (int m = 0; m < 4; ++m)
#pragma unroll
            for (int n = 0; n < 4; ++n)
                acc[4 + m][n] = MFMA16(a1[m], b0v[n], acc[4 + m][n]);
        __builtin_amdgcn_s_setprio(0);
        BAR();

        // ---- P3: read a47_k1[4]; stage A_k1(s+1); MFMA m0-3 x kh1; publish kh0(s+1) ----
#pragma unroll
        for (int m = 0; m < 4; ++m) a1[m] = rd(sb, offA[m], S_KH + 2048);
        if (more) { stg(pA1, sn + S_KH + dst0); stg(pA1 + J1, sn + S_KH + dst1); }
        LGKM(4);   // drain P2's a0/b1v
        SB0();
        __builtin_amdgcn_s_setprio(1);
#pragma unroll
        for (int m = 0; m < 4; ++m)
#pragma unroll
            for (int n = 0; n < 4; ++n)
                acc[m][n] = MFMA16(a0[m], b1v[n], acc[m][n]);
        __builtin_amdgcn_s_setprio(0);
        // publish kh0(s+1): A_k0(s+1)[P1], B_k0(s+1)[P2] landed; allow P3's 2.
        if (more) { VMCNT(2); }
        BAR();

        // ---- P4: read next-tile a03_k0 + b_k0[8]; stage B_k1(s+1); MFMA m4-7 x kh1 ----
        if (more) {
#pragma unroll
            for (int m = 0; m < 4; ++m) a0[m] = rd(sn, offA[m], 0);
#pragma unroll
            for (int n = 0; n < 4; ++n) b0v[n] = rd(sn, offB[n], S_MAT);
            stg(pB1, sn + S_MAT + S_KH + dst0); stg(pB1 + J1, sn + S_MAT + S_KH + dst1);
            pA0 += BK; pA1 += BK; pB0 += BK; pB1 += BK;
            LGKM(8);   // drain P3's a1
        } else {
            LGKM(0);   // no reads issued: drain P3's a1 fully
        }
        SB0();
        __builtin_amdgcn_s_setprio(1);
#pragma unroll
        for (int m = 0; m < 4; ++m)
#pragma unroll
            for (int n = 0; n < 4; ++n)
                acc[4 + m][n] = MFMA16(a1[m], b1v[n], acc[4 + m][n]);
        __builtin_amdgcn_s_setprio(0);
        BAR();
    }

    // ---------------- fused epilogue: scale + bias + quant + dequant ----
    const float wscale = wsp[0];
    const float oscale = osp[0];
    const int row0 = bm * BM + wm * 128;
    const int col0 = bn * BN + wn * 64;
#pragma unroll
    for (int n = 0; n < 4; ++n) {
        const int col = col0 + n * 16 + lr;
        const float bc = bias[col];
#pragma unroll
        for (int m = 0; m < 8; ++m) {
#pragma unroll
            for (int j = 0; j < 4; ++j) {
                const int row = row0 + m * 16 + kq * 4 + j;
                float y = acc[m][n][j] * wscale + bc;
                float q = rintf(y / oscale);          // round-half-even, matches jnp.round
                q = fminf(fmaxf(q, -128.0f), 127.0f);
                C[(size_t)row * O_FEAT + col] = q * oscale;
            }
        }
    }
}

extern "C" void kernel_launch(void* const* d_in, const int* in_sizes, int n_in,
                              void* d_out, int out_size, void* d_ws, size_t ws_size,
                              hipStream_t stream) {
    const float* x        = (const float*)d_in[0];  // [8192,4096] fp32
    const float* wq       = (const float*)d_in[1];  // [4096,4096] fp32 (int8 values)
    const float* bias     = (const float*)d_in[2];  // [4096]
    const float* w_scale  = (const float*)d_in[3];  // scalar
    const float* out_scale= (const float*)d_in[4];  // scalar
    const int*   mask     = (const int*)d_in[5];    // [4096,1024] int32
    float* out = (float*)d_out;

    _Float16* xf = (_Float16*)d_ws;                                        // 64 MiB
    _Float16* wf = (_Float16*)((char*)d_ws + (size_t)M_TOK * K_FEAT * 2);  // +32 MiB

    cvt_x_kernel<<<(M_TOK * (size_t)K_FEAT) / 8 / 256, 256, 0, stream>>>(x, xf);
    cvt_w_kernel<<<(O_FEAT * (size_t)K_FEAT) / 8 / 256, 256, 0, stream>>>(wq, mask, wf);

    // (8192/256) x (4096/256) = 32*16 = 512 blocks, 512 threads
    gemm_kernel<<<dim3((M_TOK / BM) * (O_FEAT / BN)), 512, 0, stream>>>(
        xf, wf, bias, w_scale, out_scale, out);
}

// Round 12
// 293.355 us; speedup vs baseline: 3.0734x; 1.0059x over previous
//
#include <hip/hip_runtime.h>

// Linear(int8-weight, block-sparse) -> quantize -> dequantize, as one fp16 MFMA GEMM.
// out[n,o] = dq(q( (x @ (w_q*mask)^T) * w_scale + bias ))
// N=8192 tokens, O=4096, K=4096.
//
// Numerics: w_q*mask integers in [-127,127] exact in fp16 (validated absmax 0.0625).
//
// GEMM: 256x256, BK=64, 8 waves (2Mx4N), BALANCED 4-phase pipeline:
// reads 6/6/6/6 per wave per phase (r11 was 4/8/4/8 -- heavy phases
// overflowed the 621-cyc MFMA window), ONE vmcnt publish per K-tile
// (end-P2, VMCNT(4)), stages one pane per phase into the CURRENT buffer
// (pane liveness: b0v for tile s is pre-read into regs at P3/P4(s-1), so
// B_k0(s) pane is dead from P1(s); each pane staged exactly one phase
// after its last LDS read, made WAR-safe by a trailing LGKM(0) after each
// MFMA cluster -- the reads ran under the MFMA, so the drain is ~free).
//   P1: rd a47_k0(sb)+b1v01(sb);  stg B_k0(s+2)->sb;  MFMA m03.kh0
//   P2: rd a03_k1(sb)+b1v23(sb);  stg A_k0(s+2)->sb;  MFMA m47.kh0; publish
//   P3: rd a47_k1(sb)+b0v01'(sn); stg B_k1(s+2)->sb;  MFMA m03.kh1
//   P4: rd a03_k0'(sn)+b0v23'(sn);stg A_k1(s+2)->sb;  MFMA m47.kh1
// Publish audit: end-P2(s) VMCNT(4) leaves P1,P2(s) stages outstanding ->
// everything staged through P4(s-1) (all of buf(s+1)) landed; flight 2-5
// phases. Tail: s>=NT-2 -> VMCNT(0) (P3,P4(NT-3) stages are the allowed-4
// at the prior publish). Pre-MFMA lgkm waits left to the compiler (operands
// always drained one phase earlier -> it emits a free lgkmcnt(6)).
// T2 granule-XOR swizzle unchanged (rounds 2-11: 0 bank conflicts).

#define M_TOK 8192
#define O_FEAT 4096
#define K_FEAT 4096

#define BM 256
#define BN 256
#define BK 64
#define NT (K_FEAT / BK)   // 64 K-tiles

// LDS element strides for smem[2][2][2][BM*32]: buf=32768, mat=16384, kh=8192
#define S_BUF 32768
#define S_MAT 16384
#define S_KH  8192

using f16x8 = __attribute__((ext_vector_type(8))) _Float16;
using f32x4 = __attribute__((ext_vector_type(4))) float;

#define BAR()    asm volatile("s_barrier" ::: "memory")
#define LGKM0()  asm volatile("s_waitcnt lgkmcnt(0)" ::: "memory")
#define VMCNT(n) asm volatile("s_waitcnt vmcnt(" #n ")" ::: "memory")
#define SB0()    __builtin_amdgcn_sched_barrier(0)
#define MFMA16(a, b, c) __builtin_amdgcn_mfma_f32_16x16x32_f16((a), (b), (c), 0, 0, 0)

#define NXBLK (M_TOK * K_FEAT / 8 / 256)   // 16384 x-blocks

// ------------- fused fp32->fp16 conversion (x) + mask-fuse (w) ---------
__global__ __launch_bounds__(256) void cvt_kernel(const float* __restrict__ x,
                                                  const float* __restrict__ wq,
                                                  const int* __restrict__ mask,
                                                  _Float16* __restrict__ xf,
                                                  _Float16* __restrict__ wf) {
    const int b = blockIdx.x;
    if (b < NXBLK) {
        size_t i = ((size_t)b * 256 + threadIdx.x) * 8;
        float4 v0 = *reinterpret_cast<const float4*>(x + i);
        float4 v1 = *reinterpret_cast<const float4*>(x + i + 4);
        f16x8 h;
        h[0] = (_Float16)v0.x; h[1] = (_Float16)v0.y;
        h[2] = (_Float16)v0.z; h[3] = (_Float16)v0.w;
        h[4] = (_Float16)v1.x; h[5] = (_Float16)v1.y;
        h[6] = (_Float16)v1.z; h[7] = (_Float16)v1.w;
        *reinterpret_cast<f16x8*>(xf + i) = h;
    } else {
        size_t i = ((size_t)(b - NXBLK) * 256 + threadIdx.x) * 8;
        float4 v0 = *reinterpret_cast<const float4*>(wq + i);
        float4 v1 = *reinterpret_cast<const float4*>(wq + i + 4);
        int2 mv = *reinterpret_cast<const int2*>(mask + i / 4);
        float m0 = mv.x ? 1.0f : 0.0f;
        float m1 = mv.y ? 1.0f : 0.0f;
        f16x8 h;
        h[0] = (_Float16)(v0.x * m0); h[1] = (_Float16)(v0.y * m0);
        h[2] = (_Float16)(v0.z * m0); h[3] = (_Float16)(v0.w * m0);
        h[4] = (_Float16)(v1.x * m1); h[5] = (_Float16)(v1.y * m1);
        h[6] = (_Float16)(v1.z * m1); h[7] = (_Float16)(v1.w * m1);
        *reinterpret_cast<f16x8*>(wf + i) = h;
    }
}

// ---------------- 256x256 balanced 4-phase fp16 MFMA GEMM ---------------
// A [8192][4096] f16 row-major, B [4096][4096] f16 row-major (B^T GEMM).
// Swizzle: 16B granule kq -> kq ^ ((row>>1)&3); linear LDS dest +
// inverse-permuted global src (global_load_lds), same XOR on ds_read.
__global__ __launch_bounds__(512, 2) void gemm_kernel(const _Float16* __restrict__ A,
                                                      const _Float16* __restrict__ B,
                                                      const float* __restrict__ bias,
                                                      const float* __restrict__ wsp,
                                                      const float* __restrict__ osp,
                                                      float* __restrict__ C) {
    __shared__ __align__(16) _Float16 smem[2][2][2][BM * 32];
    _Float16* sm = &smem[0][0][0][0];

    const int tid  = threadIdx.x;
    const int lane = tid & 63;
    const int w    = tid >> 6;      // 0..7
    const int wm   = w >> 2;        // 0..1  (M half)
    const int wn   = w & 3;         // 0..3  (N quarter)
    const int lr   = lane & 15;     // fragment row/col
    const int kq   = lane >> 4;     // 0..3  k-granule

    const int bm = blockIdx.x >> 4; // 32 M-tiles
    const int bn = blockIdx.x & 15; // 16 N-tiles

    // ---- staging geometry (hoisted advancing pointers) ----
    const int sr0  = w * 32 + (lane >> 2);
    const int csrc = ((lane & 3) ^ ((lane >> 3) & 3)) * 8;  // inverse-swizzled src granule
    const size_t J1 = (size_t)16 * K_FEAT;                  // j=1 source row offset

    const _Float16* pA0 = A + (size_t)(bm * BM + sr0) * K_FEAT + csrc;  // A kh0
    const _Float16* pA1 = pA0 + 32;                                      // A kh1
    const _Float16* pB0 = B + (size_t)(bn * BN + sr0) * K_FEAT + csrc;  // B kh0
    const _Float16* pB1 = pB0 + 32;                                      // B kh1

    const int dst0 = (w * 128 + lane) * 8;   // j=0 LDS dst elem offset within a pane
    const int dst1 = dst0 + 64 * 8;          // j=1

    auto stg = [&](const _Float16* src, const _Float16* dstp) {
        __builtin_amdgcn_global_load_lds(
            (const __attribute__((address_space(1))) void*)(const void*)src,
            (__attribute__((address_space(3))) void*)(void*)(_Float16*)(uintptr_t)dstp,
            16, 0, 0);
    };

    // ---- fragment read offsets (hoisted, swizzled) ----
    int offA[4], offB[4];
#pragma unroll
    for (int m = 0; m < 4; ++m) {
        const int r = wm * 128 + m * 16 + lr;
        offA[m] = r * 32 + ((kq ^ ((r >> 1) & 3)) << 3);
    }
#pragma unroll
    for (int n = 0; n < 4; ++n) {
        const int r = wn * 64 + n * 16 + lr;
        offB[n] = r * 32 + ((kq ^ ((r >> 1) & 3)) << 3);
    }
    auto rd = [&](const _Float16* sbuf, int off, int immE) -> f16x8 {
        return *reinterpret_cast<const f16x8*>(sbuf + off + immE);  // immE folds into ds offset
    };

    f32x4 acc[8][4] = {};
    f16x8 a0[4], a1[4], b0v[4], b1v[4];

    // ---- prologue: stage tile0->buf0, tile1->buf1 (16 loads) ----
    stg(pA0, sm + dst0);                 stg(pA0 + J1, sm + dst1);
    stg(pB0, sm + S_MAT + dst0);         stg(pB0 + J1, sm + S_MAT + dst1);
    stg(pA1, sm + S_KH + dst0);          stg(pA1 + J1, sm + S_KH + dst1);
    stg(pB1, sm + S_MAT + S_KH + dst0);  stg(pB1 + J1, sm + S_MAT + S_KH + dst1);
    pA0 += BK; pA1 += BK; pB0 += BK; pB1 += BK;   // -> tile 1
    stg(pA0, sm + S_BUF + dst0);                 stg(pA0 + J1, sm + S_BUF + dst1);
    stg(pB0, sm + S_BUF + S_MAT + dst0);         stg(pB0 + J1, sm + S_BUF + S_MAT + dst1);
    stg(pA1, sm + S_BUF + S_KH + dst0);          stg(pA1 + J1, sm + S_BUF + S_KH + dst1);
    stg(pB1, sm + S_BUF + S_MAT + S_KH + dst0);  stg(pB1 + J1, sm + S_BUF + S_MAT + S_KH + dst1);
    pA0 += BK; pA1 += BK; pB0 += BK; pB1 += BK;   // -> tile 2 (first staged in-loop)
    VMCNT(8);   // tile0 landed; tile1 in flight
    BAR();
    // prime P1(0) operands from buf0, then drain+barrier (P1/P2(0) stages
    // overwrite buf0.B_k0 / buf0.A_k0 -- the panes these reads touch)
#pragma unroll
    for (int m = 0; m < 4; ++m) a0[m] = rd(sm, offA[m], 0);
#pragma unroll
    for (int n = 0; n < 4; ++n) b0v[n] = rd(sm, offB[n], S_MAT);
    LGKM0();
    BAR();

    for (int s = 0; s < NT; ++s) {
        const _Float16* sb = sm + ((s & 1) ? S_BUF : 0);   // current buf
        const _Float16* sn = sm + ((s & 1) ? 0 : S_BUF);   // next buf
        const bool more = (s + 1 < NT);
        const bool stg_ok = (s + 2 < NT);

        // ---- P1: rd a47_k0 + b1v01 (6); stg B_k0(s+2)->sb; MFMA m03.kh0 ----
#pragma unroll
        for (int m = 0; m < 4; ++m) a1[m] = rd(sb, offA[m], 2048);
        b1v[0] = rd(sb, offB[0], S_MAT + S_KH);
        b1v[1] = rd(sb, offB[1], S_MAT + S_KH);
        if (stg_ok) { stg(pB0, sb + S_MAT + dst0); stg(pB0 + J1, sb + S_MAT + dst1); }
        SB0();
        __builtin_amdgcn_s_setprio(1);
#pragma unroll
        for (int m = 0; m < 4; ++m)
#pragma unroll
            for (int n = 0; n < 4; ++n)
                acc[m][n] = MFMA16(a0[m], b0v[n], acc[m][n]);
        __builtin_amdgcn_s_setprio(0);
        SB0(); LGKM0();   // own reads ran under the MFMA; drain for WAR
        BAR();

        // ---- P2: rd a03_k1 + b1v23 (6); stg A_k0(s+2)->sb; MFMA m47.kh0; publish ----
#pragma unroll
        for (int m = 0; m < 4; ++m) a0[m] = rd(sb, offA[m], S_KH);
        b1v[2] = rd(sb, offB[2], S_MAT + S_KH);
        b1v[3] = rd(sb, offB[3], S_MAT + S_KH);
        if (stg_ok) { stg(pA0, sb + dst0); stg(pA0 + J1, sb + dst1); }
        SB0();
        __builtin_amdgcn_s_setprio(1);
#pragma unroll
        for (int m = 0; m < 4; ++m)
#pragma unroll
            for (int n = 0; n < 4; ++n)
                acc[4 + m][n] = MFMA16(a1[m], b0v[n], acc[4 + m][n]);
        __builtin_amdgcn_s_setprio(0);
        SB0(); LGKM0();
        // publish buf(s+1): everything staged through P4(s-1) landed;
        // P1,P2(s) stages (4 loads) may stay in flight. Tail: drain all.
        if (s >= NT - 2) { VMCNT(0); } else { VMCNT(4); }
        BAR();

        // ---- P3: rd a47_k1 + b0v01'(sn) (6); stg B_k1(s+2)->sb; MFMA m03.kh1 ----
#pragma unroll
        for (int m = 0; m < 4; ++m) a1[m] = rd(sb, offA[m], S_KH + 2048);
        if (more) {
            b0v[0] = rd(sn, offB[0], S_MAT);
            b0v[1] = rd(sn, offB[1], S_MAT);
        }
        if (stg_ok) { stg(pB1, sb + S_MAT + S_KH + dst0); stg(pB1 + J1, sb + S_MAT + S_KH + dst1); }
        SB0();
        __builtin_amdgcn_s_setprio(1);
#pragma unroll
        for (int m = 0; m < 4; ++m)
#pragma unroll
            for (int n = 0; n < 4; ++n)
                acc[m][n] = MFMA16(a0[m], b1v[n], acc[m][n]);
        __builtin_amdgcn_s_setprio(0);
        SB0(); LGKM0();
        BAR();

        // ---- P4: rd a03_k0'(sn) + b0v23'(sn) (6); stg A_k1(s+2)->sb; MFMA m47.kh1 ----
        if (more) {
#pragma unroll
            for (int m = 0; m < 4; ++m) a0[m] = rd(sn, offA[m], 0);
            b0v[2] = rd(sn, offB[2], S_MAT);
            b0v[3] = rd(sn, offB[3], S_MAT);
        }
        if (stg_ok) {
            stg(pA1, sb + S_KH + dst0); stg(pA1 + J1, sb + S_KH + dst1);
        }
        SB0();
        __builtin_amdgcn_s_setprio(1);
#pragma unroll
        for (int m = 0; m < 4; ++m)
#pragma unroll
            for (int n = 0; n < 4; ++n)
                acc[4 + m][n] = MFMA16(a1[m], b1v[n], acc[4 + m][n]);
        __builtin_amdgcn_s_setprio(0);
        SB0(); LGKM0();
        BAR();

        pA0 += BK; pA1 += BK; pB0 += BK; pB1 += BK;
    }

    // ---------------- fused epilogue: scale + bias + quant + dequant ----
    const float wscale = wsp[0];
    const float oscale = osp[0];
    const int row0 = bm * BM + wm * 128;
    const int col0 = bn * BN + wn * 64;
#pragma unroll
    for (int n = 0; n < 4; ++n) {
        const int col = col0 + n * 16 + lr;
        const float bc = bias[col];
#pragma unroll
        for (int m = 0; m < 8; ++m) {
#pragma unroll
            for (int j = 0; j < 4; ++j) {
                const int row = row0 + m * 16 + kq * 4 + j;
                float y = acc[m][n][j] * wscale + bc;
                float q = rintf(y / oscale);          // round-half-even, matches jnp.round
                q = fminf(fmaxf(q, -128.0f), 127.0f);
                C[(size_t)row * O_FEAT + col] = q * oscale;
            }
        }
    }
}

extern "C" void kernel_launch(void* const* d_in, const int* in_sizes, int n_in,
                              void* d_out, int out_size, void* d_ws, size_t ws_size,
                              hipStream_t stream) {
    const float* x        = (const float*)d_in[0];  // [8192,4096] fp32
    const float* wq       = (const float*)d_in[1];  // [4096,4096] fp32 (int8 values)
    const float* bias     = (const float*)d_in[2];  // [4096]
    const float* w_scale  = (const float*)d_in[3];  // scalar
    const float* out_scale= (const float*)d_in[4];  // scalar
    const int*   mask     = (const int*)d_in[5];    // [4096,1024] int32
    float* out = (float*)d_out;

    _Float16* xf = (_Float16*)d_ws;                                        // 64 MiB
    _Float16* wf = (_Float16*)((char*)d_ws + (size_t)M_TOK * K_FEAT * 2);  // +32 MiB

    // fused cvt: 16384 x-blocks + 8192 w-blocks
    cvt_kernel<<<NXBLK + (O_FEAT * K_FEAT / 8 / 256), 256, 0, stream>>>(x, wq, mask, xf, wf);

    // (8192/256) x (4096/256) = 32*16 = 512 blocks, 512 threads
    gemm_kernel<<<dim3((M_TOK / BM) * (O_FEAT / BN)), 512, 0, stream>>>(
        xf, wf, bias, w_scale, out_scale, out);
}